// Round 1
// baseline (2103.574 us; speedup 1.0000x reference)
//
#include <hip/hip_runtime.h>
#include <hip/hip_bf16.h>

#define N_NODES 100000
#define N_EDGES 1600000

// ---------------- CSR build ----------------

__global__ __launch_bounds__(256) void k_count(const int* __restrict__ dst,
                                               int* __restrict__ deg, int e) {
    int i = blockIdx.x * 256 + threadIdx.x;
    if (i < e) atomicAdd(&deg[dst[i]], 1);
}

__global__ __launch_bounds__(256) void k_dinv(const int* __restrict__ deg,
                                              float* __restrict__ dinv, int n) {
    int i = blockIdx.x * 256 + threadIdx.x;
    if (i < n) dinv[i] = rsqrtf((float)(deg[i] + 1));  // +1 self loop; always > 0
}

__global__ __launch_bounds__(1024) void k_scan1(const int* __restrict__ cnt,
                                                int* __restrict__ rowp,
                                                int* __restrict__ bsum, int n) {
    __shared__ int buf[2][1024];
    int t = threadIdx.x;
    int gid = blockIdx.x * 1024 + t;
    int v = (gid < n) ? cnt[gid] : 0;
    int cur = 0;
    buf[0][t] = v;
    __syncthreads();
    #pragma unroll
    for (int off = 1; off < 1024; off <<= 1) {
        int x = buf[cur][t];
        if (t >= off) x += buf[cur][t - off];
        buf[cur ^ 1][t] = x;
        cur ^= 1;
        __syncthreads();
    }
    int incl = buf[cur][t];
    if (gid < n) rowp[gid] = incl - v;          // block-local exclusive
    if (t == 1023) bsum[blockIdx.x] = incl;     // block total
}

__global__ void k_scan2(const int* __restrict__ bsum, int* __restrict__ boff,
                        int nb, int* __restrict__ rowp, int n, int total) {
    if (threadIdx.x == 0) {
        int run = 0;
        for (int i = 0; i < nb; i++) { boff[i] = run; run += bsum[i]; }
        rowp[n] = total;
    }
}

__global__ __launch_bounds__(256) void k_scan3(int* __restrict__ rowp,
                                               const int* __restrict__ boff, int n) {
    int i = blockIdx.x * 256 + threadIdx.x;
    if (i < n) rowp[i] += boff[i >> 10];
}

__global__ __launch_bounds__(256) void k_fill(const int* __restrict__ ei,
                                              const float* __restrict__ dinv,
                                              const int* __restrict__ rowp,
                                              int* __restrict__ cursor,
                                              int* __restrict__ cols,
                                              float* __restrict__ nrms, int e) {
    int i = blockIdx.x * 256 + threadIdx.x;
    if (i >= e) return;
    int s = ei[i];
    int d = ei[e + i];
    int pos = atomicAdd(&cursor[d], 1);
    int slot = rowp[d] + pos;
    cols[slot] = s;
    nrms[slot] = dinv[s] * dinv[d];
}

// ---------------- GEMM: T[N,FO] = H[N,FI] @ W[FI,FO] ----------------
// BM=64 rows/block, 256 threads, per-thread 4 x (FO/16) micro-tile, K staged in 32-chunks.

template <int FI, int FO>
__global__ __launch_bounds__(256) void k_gemm(const float* __restrict__ Hin,
                                              const float* __restrict__ W,
                                              float* __restrict__ Tout, int n) {
    constexpr int BM = 64, KC = 32;
    constexpr int TN = FO / 16;  // 8 / 4 / 2
    __shared__ float As[BM][KC + 4];
    __shared__ float Ws[KC][FO];

    const int t = threadIdx.x;
    const int tx = t & 15;   // col group
    const int ty = t >> 4;   // 16 row groups of 4
    const int row0 = blockIdx.x * BM;

    float acc[4][TN];
    #pragma unroll
    for (int i = 0; i < 4; i++)
        #pragma unroll
        for (int j = 0; j < TN; j++) acc[i][j] = 0.f;

    for (int kc = 0; kc < FI; kc += KC) {
        // stage A chunk: 64x32 floats, 8 per thread (one row each)
        {
            int m = t * 8;
            int r = m >> 5;
            int k = m & 31;
            if (row0 + r < n) {
                const float4* g = reinterpret_cast<const float4*>(
                    &Hin[(size_t)(row0 + r) * FI + kc + k]);
                *reinterpret_cast<float4*>(&As[r][k])     = g[0];
                *reinterpret_cast<float4*>(&As[r][k + 4]) = g[1];
            } else {
                float4 z = {0.f, 0.f, 0.f, 0.f};
                *reinterpret_cast<float4*>(&As[r][k])     = z;
                *reinterpret_cast<float4*>(&As[r][k + 4]) = z;
            }
        }
        // stage W chunk: 32xFO floats
        for (int m = t * 4; m < KC * FO; m += 1024) {
            int k = m / FO;
            int c = m % FO;
            *reinterpret_cast<float4*>(&Ws[k][c]) =
                *reinterpret_cast<const float4*>(&W[(size_t)(kc + k) * FO + c]);
        }
        __syncthreads();

        #pragma unroll
        for (int k = 0; k < KC; k++) {
            float a[4];
            #pragma unroll
            for (int i = 0; i < 4; i++) a[i] = As[4 * ty + i][k];
            #pragma unroll
            for (int j = 0; j < TN; j++) {
                float wv = Ws[k][tx * TN + j];
                #pragma unroll
                for (int i = 0; i < 4; i++) acc[i][j] += a[i] * wv;
            }
        }
        __syncthreads();
    }

    #pragma unroll
    for (int i = 0; i < 4; i++) {
        int row = row0 + 4 * ty + i;
        if (row < n) {
            #pragma unroll
            for (int j = 0; j < TN; j++)
                Tout[(size_t)row * FO + tx * TN + j] = acc[i][j];
        }
    }
}

// ---------------- Aggregation: H[i] = relu(b + dinv[i]^2*T[i] + sum_e nrm*T[col]) ----------------
// one wave per node; lane c covers columns c, c+64

template <int FO>
__global__ __launch_bounds__(256) void k_agg(const float* __restrict__ T,
                                             const int* __restrict__ rowp,
                                             const int* __restrict__ cols,
                                             const float* __restrict__ nrms,
                                             const float* __restrict__ dinv,
                                             const float* __restrict__ bias,
                                             float* __restrict__ Hout, int n) {
    int node = blockIdx.x * 4 + (threadIdx.x >> 6);
    int lane = threadIdx.x & 63;
    if (node >= n) return;
    if (FO == 32 && lane >= 32) return;
    constexpr int NC = (FO + 63) / 64;  // 2 for 128, else 1

    float di = dinv[node];
    float dii = di * di;
    float acc[NC];
    #pragma unroll
    for (int j = 0; j < NC; j++)
        acc[j] = dii * T[(size_t)node * FO + lane + 64 * j];

    int e0 = rowp[node], e1 = rowp[node + 1];
    for (int e = e0; e < e1; e++) {
        int cs = cols[e];
        float wv = nrms[e];
        const float* tr = &T[(size_t)cs * FO];
        #pragma unroll
        for (int j = 0; j < NC; j++) acc[j] += wv * tr[lane + 64 * j];
    }

    #pragma unroll
    for (int j = 0; j < NC; j++) {
        float v = acc[j] + bias[lane + 64 * j];
        Hout[(size_t)node * FO + lane + 64 * j] = v > 0.f ? v : 0.f;
    }
}

// ---------------- Pool + FC ----------------

__global__ __launch_bounds__(256) void k_pool(const float* __restrict__ H,
                                              const int* __restrict__ batch,
                                              float* __restrict__ sums,
                                              float* __restrict__ cnt, int n) {
    int tid = blockIdx.x * 256 + threadIdx.x;
    if (tid >= n * 32) return;
    int i = tid >> 5;
    int c = tid & 31;
    int b = batch[i];
    atomicAdd(&sums[b * 32 + c], H[tid]);
    if (c == 0) atomicAdd(&cnt[b], 1.0f);
}

__global__ __launch_bounds__(256) void k_fc(const float* __restrict__ sums,
                                            const float* __restrict__ cnt,
                                            const float* __restrict__ Wfc,
                                            const float* __restrict__ bfc,
                                            float* __restrict__ out) {
    __shared__ float pooled[64 * 32];
    int t = threadIdx.x;
    for (int m = t; m < 64 * 32; m += 256) {
        int g = m >> 5;
        pooled[m] = sums[m] / fmaxf(cnt[g], 1.0f);
    }
    __syncthreads();
    for (int o = t; o < 640; o += 256) {
        int g = o / 10, c = o % 10;
        float a = bfc[c];
        #pragma unroll
        for (int k = 0; k < 32; k++) a += pooled[g * 32 + k] * Wfc[k * 10 + c];
        out[o] = a;
    }
}

// ---------------- launch ----------------

extern "C" void kernel_launch(void* const* d_in, const int* in_sizes, int n_in,
                              void* d_out, int out_size, void* d_ws, size_t ws_size,
                              hipStream_t stream) {
    const int N = N_NODES, E = N_EDGES;

    const float* x     = (const float*)d_in[0];
    const int*   ei    = (const int*)d_in[1];
    const int*   batch = (const int*)d_in[2];
    const float* W1 = (const float*)d_in[3];  const float* b1 = (const float*)d_in[4];
    const float* W2 = (const float*)d_in[5];  const float* b2 = (const float*)d_in[6];
    const float* W3 = (const float*)d_in[7];  const float* b3 = (const float*)d_in[8];
    const float* W4 = (const float*)d_in[9];  const float* b4 = (const float*)d_in[10];
    const float* W5 = (const float*)d_in[11]; const float* b5 = (const float*)d_in[12];
    const float* Wfc = (const float*)d_in[13]; const float* bfc = (const float*)d_in[14];
    float* out = (float*)d_out;

    char* p = (char*)d_ws;
    auto take = [&](size_t b) { char* q = p; p += (b + 511) & ~(size_t)511; return q; };
    int*   deg    = (int*)take((size_t)N * 4);
    int*   cursor = (int*)take((size_t)N * 4);
    int*   rowp   = (int*)take((size_t)(N + 1) * 4);
    int*   bsum   = (int*)take(512);
    int*   boff   = (int*)take(512);
    float* dinv   = (float*)take((size_t)N * 4);
    float* sums   = (float*)take((64 * 32 + 64) * 4);  // cnt appended
    float* cnt    = sums + 64 * 32;
    int*   cols   = (int*)take((size_t)E * 4);
    float* nrms   = (float*)take((size_t)E * 4);
    float* T      = (float*)take((size_t)N * 128 * 4);
    float* H      = (float*)take((size_t)N * 128 * 4);

    hipMemsetAsync(deg, 0, (size_t)N * 4, stream);
    hipMemsetAsync(cursor, 0, (size_t)N * 4, stream);
    hipMemsetAsync(sums, 0, (64 * 32 + 64) * 4, stream);

    const int eb = (E + 255) / 256;          // 6250
    const int nb = (N + 255) / 256;          // 391
    const int sb = (N + 1023) / 1024;        // 98

    k_count<<<eb, 256, 0, stream>>>(ei + E, deg, E);
    k_dinv<<<nb, 256, 0, stream>>>(deg, dinv, N);
    k_scan1<<<sb, 1024, 0, stream>>>(deg, rowp, bsum, N);
    k_scan2<<<1, 1, 0, stream>>>(bsum, boff, sb, rowp, N, E);
    k_scan3<<<nb, 256, 0, stream>>>(rowp, boff, N);
    k_fill<<<eb, 256, 0, stream>>>(ei, dinv, rowp, cursor, cols, nrms, E);

    const int gemmb = (N + 63) / 64;         // 1563
    const int aggb  = (N + 3) / 4;           // 25000

    k_gemm<128, 128><<<gemmb, 256, 0, stream>>>(x, W1, T, N);
    k_agg<128><<<aggb, 256, 0, stream>>>(T, rowp, cols, nrms, dinv, b1, H, N);

    k_gemm<128, 128><<<gemmb, 256, 0, stream>>>(H, W2, T, N);
    k_agg<128><<<aggb, 256, 0, stream>>>(T, rowp, cols, nrms, dinv, b2, H, N);

    k_gemm<128, 128><<<gemmb, 256, 0, stream>>>(H, W3, T, N);
    k_agg<128><<<aggb, 256, 0, stream>>>(T, rowp, cols, nrms, dinv, b3, H, N);

    k_gemm<128, 64><<<gemmb, 256, 0, stream>>>(H, W4, T, N);
    k_agg<64><<<aggb, 256, 0, stream>>>(T, rowp, cols, nrms, dinv, b4, H, N);

    k_gemm<64, 32><<<gemmb, 256, 0, stream>>>(H, W5, T, N);
    k_agg<32><<<aggb, 256, 0, stream>>>(T, rowp, cols, nrms, dinv, b5, H, N);

    k_pool<<<(N * 32 + 255) / 256, 256, 0, stream>>>(H, batch, sums, cnt, N);
    k_fc<<<1, 256, 0, stream>>>(sums, cnt, Wfc, bfc, out);
}

// Round 2
// 1332.965 us; speedup vs baseline: 1.5781x; 1.5781x over previous
//
#include <hip/hip_runtime.h>
#include <hip/hip_bf16.h>

#define N_NODES 100000
#define N_EDGES 1600000
#define N_GRAPHS 64

// ---------------- CSR build ----------------

__global__ __launch_bounds__(256) void k_count(const int* __restrict__ dst,
                                               int* __restrict__ deg, int e) {
    int i = blockIdx.x * 256 + threadIdx.x;
    if (i < e) atomicAdd(&deg[dst[i]], 1);
}

__global__ __launch_bounds__(256) void k_dinv(const int* __restrict__ deg,
                                              float* __restrict__ dinv, int n) {
    int i = blockIdx.x * 256 + threadIdx.x;
    if (i < n) dinv[i] = rsqrtf((float)(deg[i] + 1));  // +1 self loop; always > 0
}

__global__ __launch_bounds__(1024) void k_scan1(const int* __restrict__ cnt,
                                                int* __restrict__ rowp,
                                                int* __restrict__ bsum, int n) {
    __shared__ int buf[2][1024];
    int t = threadIdx.x;
    int gid = blockIdx.x * 1024 + t;
    int v = (gid < n) ? cnt[gid] : 0;
    int cur = 0;
    buf[0][t] = v;
    __syncthreads();
    #pragma unroll
    for (int off = 1; off < 1024; off <<= 1) {
        int x = buf[cur][t];
        if (t >= off) x += buf[cur][t - off];
        buf[cur ^ 1][t] = x;
        cur ^= 1;
        __syncthreads();
    }
    int incl = buf[cur][t];
    if (gid < n) rowp[gid] = incl - v;          // block-local exclusive
    if (t == 1023) bsum[blockIdx.x] = incl;     // block total
}

__global__ void k_scan2(const int* __restrict__ bsum, int* __restrict__ boff,
                        int nb, int* __restrict__ rowp, int n, int total) {
    if (threadIdx.x == 0) {
        int run = 0;
        for (int i = 0; i < nb; i++) { boff[i] = run; run += bsum[i]; }
        rowp[n] = total;
    }
}

__global__ __launch_bounds__(256) void k_scan3(int* __restrict__ rowp,
                                               const int* __restrict__ boff, int n) {
    int i = blockIdx.x * 256 + threadIdx.x;
    if (i < n) rowp[i] += boff[i >> 10];
}

__global__ __launch_bounds__(256) void k_fill(const int* __restrict__ ei,
                                              const float* __restrict__ dinv,
                                              const int* __restrict__ rowp,
                                              int* __restrict__ cursor,
                                              int* __restrict__ cols,
                                              float* __restrict__ nrms, int e) {
    int i = blockIdx.x * 256 + threadIdx.x;
    if (i >= e) return;
    int s = ei[i];
    int d = ei[e + i];
    int pos = atomicAdd(&cursor[d], 1);
    int slot = rowp[d] + pos;
    cols[slot] = s;
    nrms[slot] = dinv[s] * dinv[d];
}

// ---------------- GEMM: T[N,FO] = H[N,FI] @ W[FI,FO] ----------------

template <int FI, int FO>
__global__ __launch_bounds__(256) void k_gemm(const float* __restrict__ Hin,
                                              const float* __restrict__ W,
                                              float* __restrict__ Tout, int n) {
    constexpr int BM = 64, KC = 32;
    constexpr int TN = FO / 16;  // 8 / 4 / 2
    __shared__ float As[BM][KC + 4];
    __shared__ float Ws[KC][FO];

    const int t = threadIdx.x;
    const int tx = t & 15;   // col group
    const int ty = t >> 4;   // 16 row groups of 4
    const int row0 = blockIdx.x * BM;

    float acc[4][TN];
    #pragma unroll
    for (int i = 0; i < 4; i++)
        #pragma unroll
        for (int j = 0; j < TN; j++) acc[i][j] = 0.f;

    for (int kc = 0; kc < FI; kc += KC) {
        {
            int m = t * 8;
            int r = m >> 5;
            int k = m & 31;
            if (row0 + r < n) {
                const float4* g = reinterpret_cast<const float4*>(
                    &Hin[(size_t)(row0 + r) * FI + kc + k]);
                *reinterpret_cast<float4*>(&As[r][k])     = g[0];
                *reinterpret_cast<float4*>(&As[r][k + 4]) = g[1];
            } else {
                float4 z = {0.f, 0.f, 0.f, 0.f};
                *reinterpret_cast<float4*>(&As[r][k])     = z;
                *reinterpret_cast<float4*>(&As[r][k + 4]) = z;
            }
        }
        for (int m = t * 4; m < KC * FO; m += 1024) {
            int k = m / FO;
            int c = m % FO;
            *reinterpret_cast<float4*>(&Ws[k][c]) =
                *reinterpret_cast<const float4*>(&W[(size_t)(kc + k) * FO + c]);
        }
        __syncthreads();

        #pragma unroll
        for (int k = 0; k < KC; k++) {
            float a[4];
            #pragma unroll
            for (int i = 0; i < 4; i++) a[i] = As[4 * ty + i][k];
            #pragma unroll
            for (int j = 0; j < TN; j++) {
                float wv = Ws[k][tx * TN + j];
                #pragma unroll
                for (int i = 0; i < 4; i++) acc[i][j] += a[i] * wv;
            }
        }
        __syncthreads();
    }

    #pragma unroll
    for (int i = 0; i < 4; i++) {
        int row = row0 + 4 * ty + i;
        if (row < n) {
            #pragma unroll
            for (int j = 0; j < TN; j++)
                Tout[(size_t)row * FO + tx * TN + j] = acc[i][j];
        }
    }
}

// ---------------- Aggregation ----------------

template <int FO>
__global__ __launch_bounds__(256) void k_agg(const float* __restrict__ T,
                                             const int* __restrict__ rowp,
                                             const int* __restrict__ cols,
                                             const float* __restrict__ nrms,
                                             const float* __restrict__ dinv,
                                             const float* __restrict__ bias,
                                             float* __restrict__ Hout, int n) {
    int node = blockIdx.x * 4 + (threadIdx.x >> 6);
    int lane = threadIdx.x & 63;
    if (node >= n) return;
    if (FO == 32 && lane >= 32) return;
    constexpr int NC = (FO + 63) / 64;  // 2 for 128, else 1

    float di = dinv[node];
    float dii = di * di;
    float acc[NC];
    #pragma unroll
    for (int j = 0; j < NC; j++)
        acc[j] = dii * T[(size_t)node * FO + lane + 64 * j];

    int e0 = rowp[node], e1 = rowp[node + 1];
    for (int e = e0; e < e1; e++) {
        int cs = cols[e];
        float wv = nrms[e];
        const float* tr = &T[(size_t)cs * FO];
        #pragma unroll
        for (int j = 0; j < NC; j++) acc[j] += wv * tr[lane + 64 * j];
    }

    #pragma unroll
    for (int j = 0; j < NC; j++) {
        float v = acc[j] + bias[lane + 64 * j];
        Hout[(size_t)node * FO + lane + 64 * j] = v > 0.f ? v : 0.f;
    }
}

// ---------------- Pool (segmented, no atomics) + FC ----------------

// batch is sorted: start[g] = lower_bound(batch, g); start[N_GRAPHS] = n
__global__ __launch_bounds__(128) void k_bounds(const int* __restrict__ batch,
                                                int* __restrict__ start, int n) {
    int g = threadIdx.x;
    if (g > N_GRAPHS) return;
    int lo = 0, hi = n;
    while (lo < hi) {
        int mid = (lo + hi) >> 1;
        if (batch[mid] < g) lo = mid + 1; else hi = mid;
    }
    start[g] = lo;
}

// one block per graph; pooled[g*32+c] = mean of H[start[g]:start[g+1], c]
__global__ __launch_bounds__(256) void k_pool2(const float* __restrict__ H,
                                               const int* __restrict__ start,
                                               float* __restrict__ pooled) {
    __shared__ float red[256];
    int g = blockIdx.x;
    int s = start[g], e = start[g + 1];
    int t = threadIdx.x;
    int c = t & 31;       // column
    int grp = t >> 5;     // 8 row-groups
    float acc = 0.f;
    for (int i = s + grp; i < e; i += 8) acc += H[(size_t)i * 32 + c];
    red[t] = acc;
    __syncthreads();
    if (grp < 4) red[t] += red[t + 128];
    __syncthreads();
    if (grp < 2) red[t] += red[t + 64];
    __syncthreads();
    if (grp == 0) {
        float v = red[t] + red[t + 32];
        float cnt = (float)(e - s);
        pooled[g * 32 + c] = v / fmaxf(cnt, 1.0f);
    }
}

__global__ __launch_bounds__(256) void k_fc(const float* __restrict__ pooled,
                                            const float* __restrict__ Wfc,
                                            const float* __restrict__ bfc,
                                            float* __restrict__ out) {
    __shared__ float pl[N_GRAPHS * 32];
    int t = threadIdx.x;
    for (int m = t; m < N_GRAPHS * 32; m += 256) pl[m] = pooled[m];
    __syncthreads();
    for (int o = t; o < N_GRAPHS * 10; o += 256) {
        int g = o / 10, c = o % 10;
        float a = bfc[c];
        #pragma unroll
        for (int k = 0; k < 32; k++) a += pl[g * 32 + k] * Wfc[k * 10 + c];
        out[o] = a;
    }
}

// ---------------- launch ----------------

extern "C" void kernel_launch(void* const* d_in, const int* in_sizes, int n_in,
                              void* d_out, int out_size, void* d_ws, size_t ws_size,
                              hipStream_t stream) {
    const int N = N_NODES, E = N_EDGES;

    const float* x     = (const float*)d_in[0];
    const int*   ei    = (const int*)d_in[1];
    const int*   batch = (const int*)d_in[2];
    const float* W1 = (const float*)d_in[3];  const float* b1 = (const float*)d_in[4];
    const float* W2 = (const float*)d_in[5];  const float* b2 = (const float*)d_in[6];
    const float* W3 = (const float*)d_in[7];  const float* b3 = (const float*)d_in[8];
    const float* W4 = (const float*)d_in[9];  const float* b4 = (const float*)d_in[10];
    const float* W5 = (const float*)d_in[11]; const float* b5 = (const float*)d_in[12];
    const float* Wfc = (const float*)d_in[13]; const float* bfc = (const float*)d_in[14];
    float* out = (float*)d_out;

    char* p = (char*)d_ws;
    auto take = [&](size_t b) { char* q = p; p += (b + 511) & ~(size_t)511; return q; };
    int*   deg    = (int*)take((size_t)N * 4);
    int*   cursor = (int*)take((size_t)N * 4);
    int*   rowp   = (int*)take((size_t)(N + 1) * 4);
    int*   bsum   = (int*)take(512);
    int*   boff   = (int*)take(512);
    float* dinv   = (float*)take((size_t)N * 4);
    int*   gstart = (int*)take((N_GRAPHS + 1) * 4);
    float* pooled = (float*)take(N_GRAPHS * 32 * 4);
    int*   cols   = (int*)take((size_t)E * 4);
    float* nrms   = (float*)take((size_t)E * 4);
    float* T      = (float*)take((size_t)N * 128 * 4);
    float* H      = (float*)take((size_t)N * 128 * 4);

    hipMemsetAsync(deg, 0, (size_t)N * 4, stream);
    hipMemsetAsync(cursor, 0, (size_t)N * 4, stream);

    const int eb = (E + 255) / 256;
    const int nb = (N + 255) / 256;
    const int sb = (N + 1023) / 1024;

    k_count<<<eb, 256, 0, stream>>>(ei + E, deg, E);
    k_dinv<<<nb, 256, 0, stream>>>(deg, dinv, N);
    k_scan1<<<sb, 1024, 0, stream>>>(deg, rowp, bsum, N);
    k_scan2<<<1, 1, 0, stream>>>(bsum, boff, sb, rowp, N, E);
    k_scan3<<<nb, 256, 0, stream>>>(rowp, boff, N);
    k_fill<<<eb, 256, 0, stream>>>(ei, dinv, rowp, cursor, cols, nrms, E);

    const int gemmb = (N + 63) / 64;
    const int aggb  = (N + 3) / 4;

    k_gemm<128, 128><<<gemmb, 256, 0, stream>>>(x, W1, T, N);
    k_agg<128><<<aggb, 256, 0, stream>>>(T, rowp, cols, nrms, dinv, b1, H, N);

    k_gemm<128, 128><<<gemmb, 256, 0, stream>>>(H, W2, T, N);
    k_agg<128><<<aggb, 256, 0, stream>>>(T, rowp, cols, nrms, dinv, b2, H, N);

    k_gemm<128, 128><<<gemmb, 256, 0, stream>>>(H, W3, T, N);
    k_agg<128><<<aggb, 256, 0, stream>>>(T, rowp, cols, nrms, dinv, b3, H, N);

    k_gemm<128, 64><<<gemmb, 256, 0, stream>>>(H, W4, T, N);
    k_agg<64><<<aggb, 256, 0, stream>>>(T, rowp, cols, nrms, dinv, b4, H, N);

    k_gemm<64, 32><<<gemmb, 256, 0, stream>>>(H, W5, T, N);
    k_agg<32><<<aggb, 256, 0, stream>>>(T, rowp, cols, nrms, dinv, b5, H, N);

    k_bounds<<<1, 128, 0, stream>>>(batch, gstart, N);
    k_pool2<<<N_GRAPHS, 256, 0, stream>>>(H, gstart, pooled);
    k_fc<<<1, 256, 0, stream>>>(pooled, Wfc, bfc, out);
}

// Round 3
// 927.998 us; speedup vs baseline: 2.2668x; 1.4364x over previous
//
#include <hip/hip_runtime.h>
#include <hip/hip_bf16.h>

#define N_NODES 100000
#define N_EDGES 1600000
#define N_GRAPHS 64

__device__ inline float bflo(unsigned u) { return __uint_as_float(u << 16); }
__device__ inline float bfhi(unsigned u) { return __uint_as_float(u & 0xffff0000u); }
__device__ inline unsigned short f2bf(float f) {  // RNE, finite inputs
    unsigned u = __float_as_uint(f);
    return (unsigned short)((u + 0x7fff + ((u >> 16) & 1)) >> 16);
}

// ---------------- CSR build ----------------

__global__ __launch_bounds__(256) void k_count(const int* __restrict__ dst,
                                               int* __restrict__ deg, int e) {
    int i = blockIdx.x * 256 + threadIdx.x;
    if (i < e) atomicAdd(&deg[dst[i]], 1);
}

__global__ __launch_bounds__(256) void k_dinv(const int* __restrict__ deg,
                                              float* __restrict__ dinv, int n) {
    int i = blockIdx.x * 256 + threadIdx.x;
    if (i < n) dinv[i] = rsqrtf((float)(deg[i] + 1));  // +1 self loop; always > 0
}

__global__ __launch_bounds__(1024) void k_scan1(const int* __restrict__ cnt,
                                                int* __restrict__ rowp,
                                                int* __restrict__ bsum, int n) {
    __shared__ int buf[2][1024];
    int t = threadIdx.x;
    int gid = blockIdx.x * 1024 + t;
    int v = (gid < n) ? cnt[gid] : 0;
    int cur = 0;
    buf[0][t] = v;
    __syncthreads();
    #pragma unroll
    for (int off = 1; off < 1024; off <<= 1) {
        int x = buf[cur][t];
        if (t >= off) x += buf[cur][t - off];
        buf[cur ^ 1][t] = x;
        cur ^= 1;
        __syncthreads();
    }
    int incl = buf[cur][t];
    if (gid < n) rowp[gid] = incl - v;
    if (t == 1023) bsum[blockIdx.x] = incl;
}

__global__ void k_scan2(const int* __restrict__ bsum, int* __restrict__ boff,
                        int nb, int* __restrict__ rowp, int n, int total) {
    if (threadIdx.x == 0) {
        int run = 0;
        for (int i = 0; i < nb; i++) { boff[i] = run; run += bsum[i]; }
        rowp[n] = total;
    }
}

__global__ __launch_bounds__(256) void k_scan3(int* __restrict__ rowp,
                                               const int* __restrict__ boff, int n) {
    int i = blockIdx.x * 256 + threadIdx.x;
    if (i < n) rowp[i] += boff[i >> 10];
}

__global__ __launch_bounds__(256) void k_fill(const int* __restrict__ ei,
                                              const float* __restrict__ dinv,
                                              const int* __restrict__ rowp,
                                              int* __restrict__ cursor,
                                              int* __restrict__ cols,
                                              float* __restrict__ nrms, int e) {
    int i = blockIdx.x * 256 + threadIdx.x;
    if (i >= e) return;
    int s = ei[i];
    int d = ei[e + i];
    int pos = atomicAdd(&cursor[d], 1);
    int slot = rowp[d] + pos;
    cols[slot] = s;
    nrms[slot] = dinv[s] * dinv[d];
}

// ---------------- GEMM: T[N,FO](bf16) = H[N,FI](f32) @ W[FI,FO](f32) ----------------

template <int FI, int FO>
__global__ __launch_bounds__(256) void k_gemm(const float* __restrict__ Hin,
                                              const float* __restrict__ W,
                                              unsigned short* __restrict__ Tout, int n) {
    constexpr int BM = 64, KC = 32;
    constexpr int TN = FO / 16;  // 8 / 4 / 2
    __shared__ float As[BM][KC + 4];
    __shared__ float Ws[KC][FO];

    const int t = threadIdx.x;
    const int tx = t & 15;
    const int ty = t >> 4;
    const int row0 = blockIdx.x * BM;

    float acc[4][TN];
    #pragma unroll
    for (int i = 0; i < 4; i++)
        #pragma unroll
        for (int j = 0; j < TN; j++) acc[i][j] = 0.f;

    for (int kc = 0; kc < FI; kc += KC) {
        {
            int m = t * 8;
            int r = m >> 5;
            int k = m & 31;
            if (row0 + r < n) {
                const float4* g = reinterpret_cast<const float4*>(
                    &Hin[(size_t)(row0 + r) * FI + kc + k]);
                *reinterpret_cast<float4*>(&As[r][k])     = g[0];
                *reinterpret_cast<float4*>(&As[r][k + 4]) = g[1];
            } else {
                float4 z = {0.f, 0.f, 0.f, 0.f};
                *reinterpret_cast<float4*>(&As[r][k])     = z;
                *reinterpret_cast<float4*>(&As[r][k + 4]) = z;
            }
        }
        for (int m = t * 4; m < KC * FO; m += 1024) {
            int k = m / FO;
            int c = m % FO;
            *reinterpret_cast<float4*>(&Ws[k][c]) =
                *reinterpret_cast<const float4*>(&W[(size_t)(kc + k) * FO + c]);
        }
        __syncthreads();

        #pragma unroll
        for (int k = 0; k < KC; k++) {
            float a[4];
            #pragma unroll
            for (int i = 0; i < 4; i++) a[i] = As[4 * ty + i][k];
            #pragma unroll
            for (int j = 0; j < TN; j++) {
                float wv = Ws[k][tx * TN + j];
                #pragma unroll
                for (int i = 0; i < 4; i++) acc[i][j] += a[i] * wv;
            }
        }
        __syncthreads();
    }

    #pragma unroll
    for (int i = 0; i < 4; i++) {
        int row = row0 + 4 * ty + i;
        if (row < n) {
            unsigned short tmp[TN];
            #pragma unroll
            for (int j = 0; j < TN; j++) tmp[j] = f2bf(acc[i][j]);
            unsigned short* dst = &Tout[(size_t)row * FO + tx * TN];
            if constexpr (TN == 8)
                *reinterpret_cast<uint4*>(dst) = *reinterpret_cast<uint4*>(tmp);
            else if constexpr (TN == 4)
                *reinterpret_cast<uint2*>(dst) = *reinterpret_cast<uint2*>(tmp);
            else
                *reinterpret_cast<unsigned*>(dst) = *reinterpret_cast<unsigned*>(tmp);
        }
    }
}

// ---------------- Aggregation: H = relu(b + D^-1/2 A D^-1/2 T), T in bf16 ----------------
// 4 nodes/block (1 wave each). Lane pair-covers 2 cols via packed-bf16 uint load.
// FO=128: 64 lanes/edge. FO=64: 32 lanes/edge, 2 edges in flight. FO=32: 16 lanes, 4 edges.

template <int FO>
__global__ __launch_bounds__(256) void k_agg(const unsigned short* __restrict__ T,
                                             const int* __restrict__ rowp,
                                             const int* __restrict__ cols,
                                             const float* __restrict__ nrms,
                                             const float* __restrict__ dinv,
                                             const float* __restrict__ bias,
                                             float* __restrict__ Hout, int n) {
    constexpr int LPE = FO / 2;     // lanes per edge
    constexpr int EPW = 64 / LPE;   // concurrent edge slots per wave
    int node = blockIdx.x * 4 + (threadIdx.x >> 6);
    if (node >= n) return;
    int lane = threadIdx.x & 63;
    int sub = lane / LPE;
    int li  = lane % LPE;

    float acc0 = 0.f, acc1 = 0.f;
    if (sub == 0) {  // self-loop term, once
        float di = dinv[node];
        float dii = di * di;
        unsigned u = reinterpret_cast<const unsigned*>(T + (size_t)node * FO)[li];
        acc0 = dii * bflo(u);
        acc1 = dii * bfhi(u);
    }

    int e0 = rowp[node], e1 = rowp[node + 1];
    int e = e0 + sub;
    for (; e + EPW < e1; e += 2 * EPW) {   // unroll-2: two rows in flight per slot
        int   c0 = cols[e],      c1 = cols[e + EPW];
        float w0 = nrms[e],      w1 = nrms[e + EPW];
        unsigned u0 = reinterpret_cast<const unsigned*>(T + (size_t)c0 * FO)[li];
        unsigned u1 = reinterpret_cast<const unsigned*>(T + (size_t)c1 * FO)[li];
        acc0 += w0 * bflo(u0);  acc1 += w0 * bfhi(u0);
        acc0 += w1 * bflo(u1);  acc1 += w1 * bfhi(u1);
    }
    if (e < e1) {
        int c0 = cols[e];
        float w0 = nrms[e];
        unsigned u0 = reinterpret_cast<const unsigned*>(T + (size_t)c0 * FO)[li];
        acc0 += w0 * bflo(u0);  acc1 += w0 * bfhi(u0);
    }

    if constexpr (EPW >= 4) { acc0 += __shfl_xor(acc0, 16); acc1 += __shfl_xor(acc1, 16); }
    if constexpr (EPW >= 2) { acc0 += __shfl_xor(acc0, 32); acc1 += __shfl_xor(acc1, 32); }

    if (sub == 0) {
        float r0 = acc0 + bias[2 * li];
        float r1 = acc1 + bias[2 * li + 1];
        float2 st;
        st.x = r0 > 0.f ? r0 : 0.f;
        st.y = r1 > 0.f ? r1 : 0.f;
        reinterpret_cast<float2*>(Hout + (size_t)node * FO)[li] = st;
    }
}

// ---------------- Pool (segmented over sorted batch) + FC ----------------

__global__ __launch_bounds__(128) void k_bounds(const int* __restrict__ batch,
                                                int* __restrict__ start, int n) {
    int g = threadIdx.x;
    if (g > N_GRAPHS) return;
    int lo = 0, hi = n;
    while (lo < hi) {
        int mid = (lo + hi) >> 1;
        if (batch[mid] < g) lo = mid + 1; else hi = mid;
    }
    start[g] = lo;
}

__global__ __launch_bounds__(256) void k_pool2(const float* __restrict__ H,
                                               const int* __restrict__ start,
                                               float* __restrict__ pooled) {
    __shared__ float red[256];
    int g = blockIdx.x;
    int s = start[g], e = start[g + 1];
    int t = threadIdx.x;
    int c = t & 31;
    int grp = t >> 5;
    float acc = 0.f;
    for (int i = s + grp; i < e; i += 8) acc += H[(size_t)i * 32 + c];
    red[t] = acc;
    __syncthreads();
    if (grp < 4) red[t] += red[t + 128];
    __syncthreads();
    if (grp < 2) red[t] += red[t + 64];
    __syncthreads();
    if (grp == 0) {
        float v = red[t] + red[t + 32];
        float cnt = (float)(e - s);
        pooled[g * 32 + c] = v / fmaxf(cnt, 1.0f);
    }
}

__global__ __launch_bounds__(256) void k_fc(const float* __restrict__ pooled,
                                            const float* __restrict__ Wfc,
                                            const float* __restrict__ bfc,
                                            float* __restrict__ out) {
    __shared__ float pl[N_GRAPHS * 32];
    int t = threadIdx.x;
    for (int m = t; m < N_GRAPHS * 32; m += 256) pl[m] = pooled[m];
    __syncthreads();
    for (int o = t; o < N_GRAPHS * 10; o += 256) {
        int g = o / 10, c = o % 10;
        float a = bfc[c];
        #pragma unroll
        for (int k = 0; k < 32; k++) a += pl[g * 32 + k] * Wfc[k * 10 + c];
        out[o] = a;
    }
}

// ---------------- launch ----------------

extern "C" void kernel_launch(void* const* d_in, const int* in_sizes, int n_in,
                              void* d_out, int out_size, void* d_ws, size_t ws_size,
                              hipStream_t stream) {
    const int N = N_NODES, E = N_EDGES;

    const float* x     = (const float*)d_in[0];
    const int*   ei    = (const int*)d_in[1];
    const int*   batch = (const int*)d_in[2];
    const float* W1 = (const float*)d_in[3];  const float* b1 = (const float*)d_in[4];
    const float* W2 = (const float*)d_in[5];  const float* b2 = (const float*)d_in[6];
    const float* W3 = (const float*)d_in[7];  const float* b3 = (const float*)d_in[8];
    const float* W4 = (const float*)d_in[9];  const float* b4 = (const float*)d_in[10];
    const float* W5 = (const float*)d_in[11]; const float* b5 = (const float*)d_in[12];
    const float* Wfc = (const float*)d_in[13]; const float* bfc = (const float*)d_in[14];
    float* out = (float*)d_out;

    char* p = (char*)d_ws;
    auto take = [&](size_t b) { char* q = p; p += (b + 511) & ~(size_t)511; return q; };
    int*   deg    = (int*)take((size_t)N * 4);
    int*   cursor = (int*)take((size_t)N * 4);
    int*   rowp   = (int*)take((size_t)(N + 1) * 4);
    int*   bsum   = (int*)take(512);
    int*   boff   = (int*)take(512);
    float* dinv   = (float*)take((size_t)N * 4);
    int*   gstart = (int*)take((N_GRAPHS + 1) * 4);
    float* pooled = (float*)take(N_GRAPHS * 32 * 4);
    int*   cols   = (int*)take((size_t)E * 4);
    float* nrms   = (float*)take((size_t)E * 4);
    unsigned short* T = (unsigned short*)take((size_t)N * 128 * 2);  // bf16
    float* H      = (float*)take((size_t)N * 128 * 4);

    hipMemsetAsync(deg, 0, (size_t)N * 4, stream);
    hipMemsetAsync(cursor, 0, (size_t)N * 4, stream);

    const int eb = (E + 255) / 256;
    const int nb = (N + 255) / 256;
    const int sb = (N + 1023) / 1024;

    k_count<<<eb, 256, 0, stream>>>(ei + E, deg, E);
    k_dinv<<<nb, 256, 0, stream>>>(deg, dinv, N);
    k_scan1<<<sb, 1024, 0, stream>>>(deg, rowp, bsum, N);
    k_scan2<<<1, 1, 0, stream>>>(bsum, boff, sb, rowp, N, E);
    k_scan3<<<nb, 256, 0, stream>>>(rowp, boff, N);
    k_fill<<<eb, 256, 0, stream>>>(ei, dinv, rowp, cursor, cols, nrms, E);

    const int gemmb = (N + 63) / 64;
    const int aggb  = (N + 3) / 4;

    k_gemm<128, 128><<<gemmb, 256, 0, stream>>>(x, W1, T, N);
    k_agg<128><<<aggb, 256, 0, stream>>>(T, rowp, cols, nrms, dinv, b1, H, N);

    k_gemm<128, 128><<<gemmb, 256, 0, stream>>>(H, W2, T, N);
    k_agg<128><<<aggb, 256, 0, stream>>>(T, rowp, cols, nrms, dinv, b2, H, N);

    k_gemm<128, 128><<<gemmb, 256, 0, stream>>>(H, W3, T, N);
    k_agg<128><<<aggb, 256, 0, stream>>>(T, rowp, cols, nrms, dinv, b3, H, N);

    k_gemm<128, 64><<<gemmb, 256, 0, stream>>>(H, W4, T, N);
    k_agg<64><<<aggb, 256, 0, stream>>>(T, rowp, cols, nrms, dinv, b4, H, N);

    k_gemm<64, 32><<<gemmb, 256, 0, stream>>>(H, W5, T, N);
    k_agg<32><<<aggb, 256, 0, stream>>>(T, rowp, cols, nrms, dinv, b5, H, N);

    k_bounds<<<1, 128, 0, stream>>>(batch, gstart, N);
    k_pool2<<<N_GRAPHS, 256, 0, stream>>>(H, gstart, pooled);
    k_fc<<<1, 256, 0, stream>>>(pooled, Wfc, bfc, out);
}

// Round 4
// 856.900 us; speedup vs baseline: 2.4549x; 1.0830x over previous
//
#include <hip/hip_runtime.h>
#include <hip/hip_bf16.h>

#define N_NODES 100000
#define N_EDGES 1600000
#define N_GRAPHS 64

typedef __attribute__((ext_vector_type(8))) short bf16x8;
typedef __attribute__((ext_vector_type(4))) float f32x4;

__device__ inline float bflo(unsigned u) { return __uint_as_float(u << 16); }
__device__ inline float bfhi(unsigned u) { return __uint_as_float(u & 0xffff0000u); }
__device__ inline unsigned short f2bf(float f) {  // RNE, finite inputs
    unsigned u = __float_as_uint(f);
    return (unsigned short)((u + 0x7fff + ((u >> 16) & 1)) >> 16);
}

// ---------------- CSR build ----------------

__global__ __launch_bounds__(256) void k_count(const int* __restrict__ dst,
                                               int* __restrict__ deg, int e) {
    int i = blockIdx.x * 256 + threadIdx.x;
    if (i < e) atomicAdd(&deg[dst[i]], 1);
}

__global__ __launch_bounds__(256) void k_dinv(const int* __restrict__ deg,
                                              float* __restrict__ dinv, int n) {
    int i = blockIdx.x * 256 + threadIdx.x;
    if (i < n) dinv[i] = rsqrtf((float)(deg[i] + 1));  // +1 self loop; always > 0
}

__global__ __launch_bounds__(1024) void k_scan1(const int* __restrict__ cnt,
                                                int* __restrict__ rowp,
                                                int* __restrict__ bsum, int n) {
    __shared__ int buf[2][1024];
    int t = threadIdx.x;
    int gid = blockIdx.x * 1024 + t;
    int v = (gid < n) ? cnt[gid] : 0;
    int cur = 0;
    buf[0][t] = v;
    __syncthreads();
    #pragma unroll
    for (int off = 1; off < 1024; off <<= 1) {
        int x = buf[cur][t];
        if (t >= off) x += buf[cur][t - off];
        buf[cur ^ 1][t] = x;
        cur ^= 1;
        __syncthreads();
    }
    int incl = buf[cur][t];
    if (gid < n) rowp[gid] = incl - v;
    if (t == 1023) bsum[blockIdx.x] = incl;
}

__global__ void k_scan2(const int* __restrict__ bsum, int* __restrict__ boff,
                        int nb, int* __restrict__ rowp, int n, int total) {
    if (threadIdx.x == 0) {
        int run = 0;
        for (int i = 0; i < nb; i++) { boff[i] = run; run += bsum[i]; }
        rowp[n] = total;
    }
}

__global__ __launch_bounds__(256) void k_scan3(int* __restrict__ rowp,
                                               const int* __restrict__ boff, int n) {
    int i = blockIdx.x * 256 + threadIdx.x;
    if (i < n) rowp[i] += boff[i >> 10];
}

// packed edge record: .x = src col, .y = norm weight (f32 bits) — ONE 8B scattered store
__global__ __launch_bounds__(256) void k_fill(const int* __restrict__ ei,
                                              const float* __restrict__ dinv,
                                              const int* __restrict__ rowp,
                                              int* __restrict__ cursor,
                                              uint2* __restrict__ edges, int e) {
    int i = blockIdx.x * 256 + threadIdx.x;
    if (i >= e) return;
    int s = ei[i];
    int d = ei[e + i];
    int pos = atomicAdd(&cursor[d], 1);
    uint2 ev;
    ev.x = (unsigned)s;
    ev.y = __float_as_uint(dinv[s] * dinv[d]);
    edges[rowp[d] + pos] = ev;
}

// ---------------- W convert + transpose: WT[FO][FI] bf16 ----------------

__global__ __launch_bounds__(256) void k_wconv(const float* __restrict__ W,
                                               unsigned short* __restrict__ WT,
                                               int FI, int FO) {
    int i = blockIdx.x * 256 + threadIdx.x;
    if (i >= FI * FO) return;
    int n_ = i / FI, k_ = i % FI;
    WT[i] = f2bf(W[(size_t)k_ * FO + n_]);
}

// ---------------- MFMA GEMM: T[N,FO](bf16) = A[N,FI] @ WT^T ----------------
// 4 waves/block, 64 rows/block; wave w owns rows [w*16, w*16+16), all FO cols.
// A-operand lane map: A[m=lane&15][k=(lane>>4)*8+j]; B dual; D: col=lane&15, row=(lane>>4)*4+reg.

template <int FI, int FO, bool AF32>
__global__ __launch_bounds__(256) void k_gemm(const void* __restrict__ Ain,
                                              const unsigned short* __restrict__ WT,
                                              unsigned short* __restrict__ Tout, int n) {
    constexpr int NT = FO / 16;   // N-tiles per wave
    constexpr int NC = FI / 32;   // K-chunks
    const int wave = threadIdx.x >> 6;
    const int lane = threadIdx.x & 63;
    const int m = lane & 15;
    const int q = lane >> 4;
    const int row0 = blockIdx.x * 64 + wave * 16;
    int arow = row0 + m;
    if (arow > n - 1) arow = n - 1;   // clamp for tail block (stores are guarded)

    f32x4 acc[NT];
    #pragma unroll
    for (int j = 0; j < NT; j++) acc[j] = (f32x4){0.f, 0.f, 0.f, 0.f};

    #pragma unroll
    for (int c = 0; c < NC; c++) {
        const int k0 = c * 32 + q * 8;
        bf16x8 a;
        if constexpr (AF32) {
            const float* ap = (const float*)Ain + (size_t)arow * FI + k0;
            float4 f0 = *reinterpret_cast<const float4*>(ap);
            float4 f1 = *reinterpret_cast<const float4*>(ap + 4);
            a[0] = (short)f2bf(f0.x); a[1] = (short)f2bf(f0.y);
            a[2] = (short)f2bf(f0.z); a[3] = (short)f2bf(f0.w);
            a[4] = (short)f2bf(f1.x); a[5] = (short)f2bf(f1.y);
            a[6] = (short)f2bf(f1.z); a[7] = (short)f2bf(f1.w);
        } else {
            a = *reinterpret_cast<const bf16x8*>(
                    (const unsigned short*)Ain + (size_t)arow * FI + k0);
        }
        #pragma unroll
        for (int j = 0; j < NT; j++) {
            bf16x8 b = *reinterpret_cast<const bf16x8*>(
                           WT + (size_t)(j * 16 + m) * FI + k0);
            acc[j] = __builtin_amdgcn_mfma_f32_16x16x32_bf16(a, b, acc[j], 0, 0, 0);
        }
    }

    #pragma unroll
    for (int r = 0; r < 4; r++) {
        int row = row0 + q * 4 + r;
        if (row < n) {
            #pragma unroll
            for (int j = 0; j < NT; j++)
                Tout[(size_t)row * FO + j * 16 + m] = f2bf(acc[j][r]);
        }
    }
}

// ---------------- Aggregation: H(bf16) = relu(b + D^-1/2 A D^-1/2 T(bf16)) ----------------

template <int FO>
__global__ __launch_bounds__(256) void k_agg(const unsigned short* __restrict__ T,
                                             const int* __restrict__ rowp,
                                             const uint2* __restrict__ edges,
                                             const float* __restrict__ dinv,
                                             const float* __restrict__ bias,
                                             unsigned short* __restrict__ Hout, int n) {
    constexpr int LPE = FO / 2;     // lanes per edge (2 cols/lane packed)
    constexpr int EPW = 64 / LPE;   // concurrent edge slots per wave
    int node = blockIdx.x * 4 + (threadIdx.x >> 6);
    if (node >= n) return;
    int lane = threadIdx.x & 63;
    int sub = lane / LPE;
    int li  = lane % LPE;

    float acc0 = 0.f, acc1 = 0.f;
    if (sub == 0) {  // self-loop term
        float di = dinv[node];
        float dii = di * di;
        unsigned u = reinterpret_cast<const unsigned*>(T + (size_t)node * FO)[li];
        acc0 = dii * bflo(u);
        acc1 = dii * bfhi(u);
    }

    int e0 = rowp[node], e1 = rowp[node + 1];
    int e = e0 + sub;
    for (; e + EPW < e1; e += 2 * EPW) {
        uint2 ea = edges[e], eb = edges[e + EPW];
        float w0 = __uint_as_float(ea.y), w1 = __uint_as_float(eb.y);
        unsigned u0 = reinterpret_cast<const unsigned*>(T + (size_t)ea.x * FO)[li];
        unsigned u1 = reinterpret_cast<const unsigned*>(T + (size_t)eb.x * FO)[li];
        acc0 += w0 * bflo(u0);  acc1 += w0 * bfhi(u0);
        acc0 += w1 * bflo(u1);  acc1 += w1 * bfhi(u1);
    }
    if (e < e1) {
        uint2 ea = edges[e];
        float w0 = __uint_as_float(ea.y);
        unsigned u0 = reinterpret_cast<const unsigned*>(T + (size_t)ea.x * FO)[li];
        acc0 += w0 * bflo(u0);  acc1 += w0 * bfhi(u0);
    }

    if constexpr (EPW >= 4) { acc0 += __shfl_xor(acc0, 16); acc1 += __shfl_xor(acc1, 16); }
    if constexpr (EPW >= 2) { acc0 += __shfl_xor(acc0, 32); acc1 += __shfl_xor(acc1, 32); }

    if (sub == 0) {
        float r0 = acc0 + bias[2 * li];
        float r1 = acc1 + bias[2 * li + 1];
        r0 = r0 > 0.f ? r0 : 0.f;
        r1 = r1 > 0.f ? r1 : 0.f;
        unsigned pk = (unsigned)f2bf(r0) | ((unsigned)f2bf(r1) << 16);
        reinterpret_cast<unsigned*>(Hout + (size_t)node * FO)[li] = pk;
    }
}

// ---------------- Pool (segmented over sorted batch, H bf16) + FC ----------------

__global__ __launch_bounds__(128) void k_bounds(const int* __restrict__ batch,
                                                int* __restrict__ start, int n) {
    int g = threadIdx.x;
    if (g > N_GRAPHS) return;
    int lo = 0, hi = n;
    while (lo < hi) {
        int mid = (lo + hi) >> 1;
        if (batch[mid] < g) lo = mid + 1; else hi = mid;
    }
    start[g] = lo;
}

__global__ __launch_bounds__(256) void k_pool2(const unsigned short* __restrict__ H,
                                               const int* __restrict__ start,
                                               float* __restrict__ pooled) {
    __shared__ float red0[256], red1[256];
    int g = blockIdx.x;
    int s = start[g], e = start[g + 1];
    int t = threadIdx.x;
    int c = t & 15;       // uint (col pair) index
    int grp = t >> 4;     // 16 row-groups
    float a0 = 0.f, a1 = 0.f;
    for (int i = s + grp; i < e; i += 16) {
        unsigned u = reinterpret_cast<const unsigned*>(H + (size_t)i * 32)[c];
        a0 += bflo(u); a1 += bfhi(u);
    }
    red0[t] = a0; red1[t] = a1;
    __syncthreads();
    for (int off = 128; off >= 16; off >>= 1) {
        if (t < off) { red0[t] += red0[t + off]; red1[t] += red1[t + off]; }
        __syncthreads();
    }
    if (t < 16) {
        float cnt = fmaxf((float)(e - s), 1.0f);
        pooled[g * 32 + 2 * t]     = red0[t] / cnt;
        pooled[g * 32 + 2 * t + 1] = red1[t] / cnt;
    }
}

__global__ __launch_bounds__(256) void k_fc(const float* __restrict__ pooled,
                                            const float* __restrict__ Wfc,
                                            const float* __restrict__ bfc,
                                            float* __restrict__ out) {
    __shared__ float pl[N_GRAPHS * 32];
    int t = threadIdx.x;
    for (int m = t; m < N_GRAPHS * 32; m += 256) pl[m] = pooled[m];
    __syncthreads();
    for (int o = t; o < N_GRAPHS * 10; o += 256) {
        int g = o / 10, c = o % 10;
        float a = bfc[c];
        #pragma unroll
        for (int k = 0; k < 32; k++) a += pl[g * 32 + k] * Wfc[k * 10 + c];
        out[o] = a;
    }
}

// ---------------- launch ----------------

extern "C" void kernel_launch(void* const* d_in, const int* in_sizes, int n_in,
                              void* d_out, int out_size, void* d_ws, size_t ws_size,
                              hipStream_t stream) {
    const int N = N_NODES, E = N_EDGES;

    const float* x     = (const float*)d_in[0];
    const int*   ei    = (const int*)d_in[1];
    const int*   batch = (const int*)d_in[2];
    const float* W1 = (const float*)d_in[3];  const float* b1 = (const float*)d_in[4];
    const float* W2 = (const float*)d_in[5];  const float* b2 = (const float*)d_in[6];
    const float* W3 = (const float*)d_in[7];  const float* b3 = (const float*)d_in[8];
    const float* W4 = (const float*)d_in[9];  const float* b4 = (const float*)d_in[10];
    const float* W5 = (const float*)d_in[11]; const float* b5 = (const float*)d_in[12];
    const float* Wfc = (const float*)d_in[13]; const float* bfc = (const float*)d_in[14];
    float* out = (float*)d_out;

    char* p = (char*)d_ws;
    auto take = [&](size_t b) { char* q = p; p += (b + 511) & ~(size_t)511; return q; };
    int*   deg    = (int*)take((size_t)N * 4);
    int*   cursor = (int*)take((size_t)N * 4);
    int*   rowp   = (int*)take((size_t)(N + 1) * 4);
    int*   bsum   = (int*)take(512);
    int*   boff   = (int*)take(512);
    float* dinv   = (float*)take((size_t)N * 4);
    int*   gstart = (int*)take((N_GRAPHS + 1) * 4);
    float* pooled = (float*)take(N_GRAPHS * 32 * 4);
    uint2* edges  = (uint2*)take((size_t)E * 8);
    unsigned short* wt1 = (unsigned short*)take(128 * 128 * 2);
    unsigned short* wt2 = (unsigned short*)take(128 * 128 * 2);
    unsigned short* wt3 = (unsigned short*)take(128 * 128 * 2);
    unsigned short* wt4 = (unsigned short*)take(128 * 64 * 2);
    unsigned short* wt5 = (unsigned short*)take(64 * 32 * 2);
    unsigned short* T   = (unsigned short*)take((size_t)N * 128 * 2);  // bf16
    unsigned short* H   = (unsigned short*)take((size_t)N * 128 * 2);  // bf16

    hipMemsetAsync(deg, 0, (size_t)N * 4, stream);
    hipMemsetAsync(cursor, 0, (size_t)N * 4, stream);

    const int eb = (E + 255) / 256;
    const int nb = (N + 255) / 256;
    const int sb = (N + 1023) / 1024;

    k_count<<<eb, 256, 0, stream>>>(ei + E, deg, E);
    k_dinv<<<nb, 256, 0, stream>>>(deg, dinv, N);
    k_scan1<<<sb, 1024, 0, stream>>>(deg, rowp, bsum, N);
    k_scan2<<<1, 1, 0, stream>>>(bsum, boff, sb, rowp, N, E);
    k_scan3<<<nb, 256, 0, stream>>>(rowp, boff, N);
    k_fill<<<eb, 256, 0, stream>>>(ei, dinv, rowp, cursor, edges, E);

    k_wconv<<<64, 256, 0, stream>>>(W1, wt1, 128, 128);
    k_wconv<<<64, 256, 0, stream>>>(W2, wt2, 128, 128);
    k_wconv<<<64, 256, 0, stream>>>(W3, wt3, 128, 128);
    k_wconv<<<32, 256, 0, stream>>>(W4, wt4, 128, 64);
    k_wconv<<<8,  256, 0, stream>>>(W5, wt5, 64, 32);

    const int gemmb = (N + 63) / 64;
    const int aggb  = (N + 3) / 4;

    k_gemm<128, 128, true ><<<gemmb, 256, 0, stream>>>(x, wt1, T, N);
    k_agg<128><<<aggb, 256, 0, stream>>>(T, rowp, edges, dinv, b1, H, N);

    k_gemm<128, 128, false><<<gemmb, 256, 0, stream>>>(H, wt2, T, N);
    k_agg<128><<<aggb, 256, 0, stream>>>(T, rowp, edges, dinv, b2, H, N);

    k_gemm<128, 128, false><<<gemmb, 256, 0, stream>>>(H, wt3, T, N);
    k_agg<128><<<aggb, 256, 0, stream>>>(T, rowp, edges, dinv, b3, H, N);

    k_gemm<128, 64, false><<<gemmb, 256, 0, stream>>>(H, wt4, T, N);
    k_agg<64><<<aggb, 256, 0, stream>>>(T, rowp, edges, dinv, b4, H, N);

    k_gemm<64, 32, false><<<gemmb, 256, 0, stream>>>(H, wt5, T, N);
    k_agg<32><<<aggb, 256, 0, stream>>>(T, rowp, edges, dinv, b5, H, N);

    k_bounds<<<1, 128, 0, stream>>>(batch, gstart, N);
    k_pool2<<<N_GRAPHS, 256, 0, stream>>>(H, gstart, pooled);
    k_fc<<<1, 256, 0, stream>>>(pooled, Wfc, bfc, out);
}

// Round 6
// 823.910 us; speedup vs baseline: 2.5532x; 1.0400x over previous
//
#include <hip/hip_runtime.h>
#include <hip/hip_bf16.h>

#define N_NODES 100000
#define N_EDGES 1600000
#define N_GRAPHS 64

typedef __attribute__((ext_vector_type(8))) short bf16x8;
typedef __attribute__((ext_vector_type(4))) float f32x4;

__device__ inline float bflo(unsigned u) { return __uint_as_float(u << 16); }
__device__ inline float bfhi(unsigned u) { return __uint_as_float(u & 0xffff0000u); }
__device__ inline unsigned short f2bf(float f) {  // RNE, finite inputs
    unsigned u = __float_as_uint(f);
    return (unsigned short)((u + 0x7fff + ((u >> 16) & 1)) >> 16);
}

// ---------------- CSR build ----------------

__global__ __launch_bounds__(256) void k_count(const int* __restrict__ dst,
                                               int* __restrict__ deg, int e) {
    int i = blockIdx.x * 256 + threadIdx.x;
    if (i < e) atomicAdd(&deg[dst[i]], 1);
}

__global__ __launch_bounds__(256) void k_dinv(const int* __restrict__ deg,
                                              float* __restrict__ dinv, int n) {
    int i = blockIdx.x * 256 + threadIdx.x;
    if (i < n) dinv[i] = rsqrtf((float)(deg[i] + 1));  // +1 self loop; always > 0
}

__global__ __launch_bounds__(1024) void k_scan1(const int* __restrict__ cnt,
                                                int* __restrict__ rowp,
                                                int* __restrict__ bsum, int n) {
    __shared__ int buf[2][1024];
    int t = threadIdx.x;
    int gid = blockIdx.x * 1024 + t;
    int v = (gid < n) ? cnt[gid] : 0;
    int cur = 0;
    buf[0][t] = v;
    __syncthreads();
    #pragma unroll
    for (int off = 1; off < 1024; off <<= 1) {
        int x = buf[cur][t];
        if (t >= off) x += buf[cur][t - off];
        buf[cur ^ 1][t] = x;
        cur ^= 1;
        __syncthreads();
    }
    int incl = buf[cur][t];
    if (gid < n) rowp[gid] = incl - v;
    if (t == 1023) bsum[blockIdx.x] = incl;
}

__global__ void k_scan2(const int* __restrict__ bsum, int* __restrict__ boff,
                        int nb, int* __restrict__ rowp, int n, int total) {
    if (threadIdx.x == 0) {
        int run = 0;
        for (int i = 0; i < nb; i++) { boff[i] = run; run += bsum[i]; }
        rowp[n] = total;
    }
}

__global__ __launch_bounds__(256) void k_scan3(int* __restrict__ rowp,
                                               const int* __restrict__ boff, int n) {
    int i = blockIdx.x * 256 + threadIdx.x;
    if (i < n) rowp[i] += boff[i >> 10];
}

// packed edge record: low32 = src col, high32 = norm weight (f32 bits) — ONE 8B store
__global__ __launch_bounds__(256) void k_fill(const int* __restrict__ ei,
                                              const float* __restrict__ dinv,
                                              const int* __restrict__ rowp,
                                              int* __restrict__ cursor,
                                              unsigned long long* __restrict__ edges, int e) {
    int i = blockIdx.x * 256 + threadIdx.x;
    if (i >= e) return;
    int s = ei[i];
    int d = ei[e + i];
    int pos = atomicAdd(&cursor[d], 1);
    unsigned long long ev = (unsigned long long)(unsigned)s |
        ((unsigned long long)__float_as_uint(dinv[s] * dinv[d]) << 32);
    edges[rowp[d] + pos] = ev;
}

// ---------------- W convert + transpose: WT[FO][FI] bf16 ----------------

__global__ __launch_bounds__(256) void k_wconv(const float* __restrict__ W,
                                               unsigned short* __restrict__ WT,
                                               int FI, int FO) {
    int i = blockIdx.x * 256 + threadIdx.x;
    if (i >= FI * FO) return;
    int n_ = i / FI, k_ = i % FI;
    WT[i] = f2bf(W[(size_t)k_ * FO + n_]);
}

// ---------------- MFMA GEMM: T[N,FO](bf16) = A[N,FI] @ WT^T ----------------
// 4 waves/block, 64 rows/block; wave w owns rows [w*16, w*16+16), all FO cols.

template <int FI, int FO, bool AF32>
__global__ __launch_bounds__(256) void k_gemm(const void* __restrict__ Ain,
                                              const unsigned short* __restrict__ WT,
                                              unsigned short* __restrict__ Tout, int n) {
    constexpr int NT = FO / 16;   // N-tiles per wave
    constexpr int NC = FI / 32;   // K-chunks
    const int wave = threadIdx.x >> 6;
    const int lane = threadIdx.x & 63;
    const int m = lane & 15;
    const int q = lane >> 4;
    const int row0 = blockIdx.x * 64 + wave * 16;
    int arow = row0 + m;
    if (arow > n - 1) arow = n - 1;   // clamp for tail block (stores are guarded)

    f32x4 acc[NT];
    #pragma unroll
    for (int j = 0; j < NT; j++) acc[j] = (f32x4){0.f, 0.f, 0.f, 0.f};

    #pragma unroll
    for (int c = 0; c < NC; c++) {
        const int k0 = c * 32 + q * 8;
        bf16x8 a;
        if constexpr (AF32) {
            const float* ap = (const float*)Ain + (size_t)arow * FI + k0;
            float4 f0 = *reinterpret_cast<const float4*>(ap);
            float4 f1 = *reinterpret_cast<const float4*>(ap + 4);
            a[0] = (short)f2bf(f0.x); a[1] = (short)f2bf(f0.y);
            a[2] = (short)f2bf(f0.z); a[3] = (short)f2bf(f0.w);
            a[4] = (short)f2bf(f1.x); a[5] = (short)f2bf(f1.y);
            a[6] = (short)f2bf(f1.z); a[7] = (short)f2bf(f1.w);
        } else {
            a = *reinterpret_cast<const bf16x8*>(
                    (const unsigned short*)Ain + (size_t)arow * FI + k0);
        }
        #pragma unroll
        for (int j = 0; j < NT; j++) {
            bf16x8 b = *reinterpret_cast<const bf16x8*>(
                           WT + (size_t)(j * 16 + m) * FI + k0);
            acc[j] = __builtin_amdgcn_mfma_f32_16x16x32_bf16(a, b, acc[j], 0, 0, 0);
        }
    }

    #pragma unroll
    for (int r = 0; r < 4; r++) {
        int row = row0 + q * 4 + r;
        if (row < n) {
            #pragma unroll
            for (int j = 0; j < NT; j++)
                Tout[(size_t)row * FO + j * 16 + m] = f2bf(acc[j][r]);
        }
    }
}

// ---------------- Aggregation: H(bf16) = relu(b + D^-1/2 A D^-1/2 T(bf16)) ----------------
// 1 wave/node, 4 nodes/block. Lane covers 4 cols via uint2; LPE=FO/4 lanes/edge,
// EPW=64/LPE edges concurrent + unroll-4 => up to 8 T-row loads in flight per wave.

template <int FO>
__global__ __launch_bounds__(256) void k_agg(const unsigned short* __restrict__ T,
                                             const int* __restrict__ rowp,
                                             const unsigned long long* __restrict__ edges,
                                             const float* __restrict__ dinv,
                                             const float* __restrict__ bias,
                                             unsigned short* __restrict__ Hout, int n) {
    constexpr int LPE = FO / 4;     // lanes per edge (4 cols/lane via uint2)
    constexpr int EPW = 64 / LPE;   // concurrent edge slots per wave
    int node = blockIdx.x * 4 + (threadIdx.x >> 6);
    if (node >= n) return;               // wave-uniform exit
    node = __builtin_amdgcn_readfirstlane(node);
    const int lane = threadIdx.x & 63;
    const int sub = lane / LPE;
    const int li  = lane % LPE;

    float acc0 = 0.f, acc1 = 0.f, acc2 = 0.f, acc3 = 0.f;
    if (sub == 0) {  // self-loop term
        float dii = dinv[node]; dii *= dii;
        uint2 u = reinterpret_cast<const uint2*>(T + (size_t)node * FO)[li];
        acc0 = dii * bflo(u.x); acc1 = dii * bfhi(u.x);
        acc2 = dii * bflo(u.y); acc3 = dii * bfhi(u.y);
    }

    const int e0 = rowp[node], e1 = rowp[node + 1];
    int e = e0 + sub;
    for (; e + 3 * EPW < e1; e += 4 * EPW) {
        unsigned long long ev0 = __builtin_nontemporal_load(&edges[e]);
        unsigned long long ev1 = __builtin_nontemporal_load(&edges[e + EPW]);
        unsigned long long ev2 = __builtin_nontemporal_load(&edges[e + 2 * EPW]);
        unsigned long long ev3 = __builtin_nontemporal_load(&edges[e + 3 * EPW]);
        uint2 t0 = reinterpret_cast<const uint2*>(T + (size_t)(unsigned)ev0 * FO)[li];
        uint2 t1 = reinterpret_cast<const uint2*>(T + (size_t)(unsigned)ev1 * FO)[li];
        uint2 t2 = reinterpret_cast<const uint2*>(T + (size_t)(unsigned)ev2 * FO)[li];
        uint2 t3 = reinterpret_cast<const uint2*>(T + (size_t)(unsigned)ev3 * FO)[li];
        float w0 = __uint_as_float((unsigned)(ev0 >> 32));
        float w1 = __uint_as_float((unsigned)(ev1 >> 32));
        float w2 = __uint_as_float((unsigned)(ev2 >> 32));
        float w3 = __uint_as_float((unsigned)(ev3 >> 32));
        acc0 += w0 * bflo(t0.x); acc1 += w0 * bfhi(t0.x);
        acc2 += w0 * bflo(t0.y); acc3 += w0 * bfhi(t0.y);
        acc0 += w1 * bflo(t1.x); acc1 += w1 * bfhi(t1.x);
        acc2 += w1 * bflo(t1.y); acc3 += w1 * bfhi(t1.y);
        acc0 += w2 * bflo(t2.x); acc1 += w2 * bfhi(t2.x);
        acc2 += w2 * bflo(t2.y); acc3 += w2 * bfhi(t2.y);
        acc0 += w3 * bflo(t3.x); acc1 += w3 * bfhi(t3.x);
        acc2 += w3 * bflo(t3.y); acc3 += w3 * bfhi(t3.y);
    }
    for (; e < e1; e += EPW) {
        unsigned long long ev = __builtin_nontemporal_load(&edges[e]);
        uint2 t0 = reinterpret_cast<const uint2*>(T + (size_t)(unsigned)ev * FO)[li];
        float w0 = __uint_as_float((unsigned)(ev >> 32));
        acc0 += w0 * bflo(t0.x); acc1 += w0 * bfhi(t0.x);
        acc2 += w0 * bflo(t0.y); acc3 += w0 * bfhi(t0.y);
    }

    #pragma unroll
    for (int off = LPE; off < 64; off <<= 1) {
        acc0 += __shfl_xor(acc0, off);
        acc1 += __shfl_xor(acc1, off);
        acc2 += __shfl_xor(acc2, off);
        acc3 += __shfl_xor(acc3, off);
    }

    if (sub == 0) {
        float4 b4 = reinterpret_cast<const float4*>(bias)[li];
        float r0 = fmaxf(acc0 + b4.x, 0.f);
        float r1 = fmaxf(acc1 + b4.y, 0.f);
        float r2 = fmaxf(acc2 + b4.z, 0.f);
        float r3 = fmaxf(acc3 + b4.w, 0.f);
        uint2 pk;
        pk.x = (unsigned)f2bf(r0) | ((unsigned)f2bf(r1) << 16);
        pk.y = (unsigned)f2bf(r2) | ((unsigned)f2bf(r3) << 16);
        reinterpret_cast<uint2*>(Hout + (size_t)node * FO)[li] = pk;
    }
}

// ---------------- Pool (segmented over sorted batch, H bf16) + FC ----------------

__global__ __launch_bounds__(128) void k_bounds(const int* __restrict__ batch,
                                                int* __restrict__ start, int n) {
    int g = threadIdx.x;
    if (g > N_GRAPHS) return;
    int lo = 0, hi = n;
    while (lo < hi) {
        int mid = (lo + hi) >> 1;
        if (batch[mid] < g) lo = mid + 1; else hi = mid;
    }
    start[g] = lo;
}

__global__ __launch_bounds__(256) void k_pool2(const unsigned short* __restrict__ H,
                                               const int* __restrict__ start,
                                               float* __restrict__ pooled) {
    __shared__ float red0[256], red1[256];
    int g = blockIdx.x;
    int s = start[g], e = start[g + 1];
    int t = threadIdx.x;
    int c = t & 15;       // uint (col pair) index
    int grp = t >> 4;     // 16 row-groups
    float a0 = 0.f, a1 = 0.f;
    for (int i = s + grp; i < e; i += 16) {
        unsigned u = reinterpret_cast<const unsigned*>(H + (size_t)i * 32)[c];
        a0 += bflo(u); a1 += bfhi(u);
    }
    red0[t] = a0; red1[t] = a1;
    __syncthreads();
    for (int off = 128; off >= 16; off >>= 1) {
        if (t < off) { red0[t] += red0[t + off]; red1[t] += red1[t + off]; }
        __syncthreads();
    }
    if (t < 16) {
        float cnt = fmaxf((float)(e - s), 1.0f);
        pooled[g * 32 + 2 * t]     = red0[t] / cnt;
        pooled[g * 32 + 2 * t + 1] = red1[t] / cnt;
    }
}

__global__ __launch_bounds__(256) void k_fc(const float* __restrict__ pooled,
                                            const float* __restrict__ Wfc,
                                            const float* __restrict__ bfc,
                                            float* __restrict__ out) {
    __shared__ float pl[N_GRAPHS * 32];
    int t = threadIdx.x;
    for (int m = t; m < N_GRAPHS * 32; m += 256) pl[m] = pooled[m];
    __syncthreads();
    for (int o = t; o < N_GRAPHS * 10; o += 256) {
        int g = o / 10, c = o % 10;
        float a = bfc[c];
        #pragma unroll
        for (int k = 0; k < 32; k++) a += pl[g * 32 + k] * Wfc[k * 10 + c];
        out[o] = a;
    }
}

// ---------------- launch ----------------

extern "C" void kernel_launch(void* const* d_in, const int* in_sizes, int n_in,
                              void* d_out, int out_size, void* d_ws, size_t ws_size,
                              hipStream_t stream) {
    const int N = N_NODES, E = N_EDGES;

    const float* x     = (const float*)d_in[0];
    const int*   ei    = (const int*)d_in[1];
    const int*   batch = (const int*)d_in[2];
    const float* W1 = (const float*)d_in[3];  const float* b1 = (const float*)d_in[4];
    const float* W2 = (const float*)d_in[5];  const float* b2 = (const float*)d_in[6];
    const float* W3 = (const float*)d_in[7];  const float* b3 = (const float*)d_in[8];
    const float* W4 = (const float*)d_in[9];  const float* b4 = (const float*)d_in[10];
    const float* W5 = (const float*)d_in[11]; const float* b5 = (const float*)d_in[12];
    const float* Wfc = (const float*)d_in[13]; const float* bfc = (const float*)d_in[14];
    float* out = (float*)d_out;

    char* p = (char*)d_ws;
    auto take = [&](size_t b) { char* q = p; p += (b + 511) & ~(size_t)511; return q; };
    int*   deg    = (int*)take((size_t)N * 4);
    int*   cursor = (int*)take((size_t)N * 4);
    int*   rowp   = (int*)take((size_t)(N + 1) * 4);
    int*   bsum   = (int*)take(512);
    int*   boff   = (int*)take(512);
    float* dinv   = (float*)take((size_t)N * 4);
    int*   gstart = (int*)take((N_GRAPHS + 1) * 4);
    float* pooled = (float*)take(N_GRAPHS * 32 * 4);
    unsigned long long* edges = (unsigned long long*)take((size_t)E * 8);
    unsigned short* wt1 = (unsigned short*)take(128 * 128 * 2);
    unsigned short* wt2 = (unsigned short*)take(128 * 128 * 2);
    unsigned short* wt3 = (unsigned short*)take(128 * 128 * 2);
    unsigned short* wt4 = (unsigned short*)take(128 * 64 * 2);
    unsigned short* wt5 = (unsigned short*)take(64 * 32 * 2);
    unsigned short* T   = (unsigned short*)take((size_t)N * 128 * 2);  // bf16
    unsigned short* H   = (unsigned short*)take((size_t)N * 128 * 2);  // bf16

    hipMemsetAsync(deg, 0, (size_t)N * 4, stream);
    hipMemsetAsync(cursor, 0, (size_t)N * 4, stream);

    const int eb = (E + 255) / 256;
    const int nb = (N + 255) / 256;
    const int sb = (N + 1023) / 1024;

    k_count<<<eb, 256, 0, stream>>>(ei + E, deg, E);
    k_dinv<<<nb, 256, 0, stream>>>(deg, dinv, N);
    k_scan1<<<sb, 1024, 0, stream>>>(deg, rowp, bsum, N);
    k_scan2<<<1, 1, 0, stream>>>(bsum, boff, sb, rowp, N, E);
    k_scan3<<<nb, 256, 0, stream>>>(rowp, boff, N);
    k_fill<<<eb, 256, 0, stream>>>(ei, dinv, rowp, cursor, edges, E);

    k_wconv<<<64, 256, 0, stream>>>(W1, wt1, 128, 128);
    k_wconv<<<64, 256, 0, stream>>>(W2, wt2, 128, 128);
    k_wconv<<<64, 256, 0, stream>>>(W3, wt3, 128, 128);
    k_wconv<<<32, 256, 0, stream>>>(W4, wt4, 128, 64);
    k_wconv<<<8,  256, 0, stream>>>(W5, wt5, 64, 32);

    const int gemmb = (N + 63) / 64;
    const int aggb  = (N + 3) / 4;

    k_gemm<128, 128, true ><<<gemmb, 256, 0, stream>>>(x, wt1, T, N);
    k_agg<128><<<aggb, 256, 0, stream>>>(T, rowp, edges, dinv, b1, H, N);

    k_gemm<128, 128, false><<<gemmb, 256, 0, stream>>>(H, wt2, T, N);
    k_agg<128><<<aggb, 256, 0, stream>>>(T, rowp, edges, dinv, b2, H, N);

    k_gemm<128, 128, false><<<gemmb, 256, 0, stream>>>(H, wt3, T, N);
    k_agg<128><<<aggb, 256, 0, stream>>>(T, rowp, edges, dinv, b3, H, N);

    k_gemm<128, 64, false><<<gemmb, 256, 0, stream>>>(H, wt4, T, N);
    k_agg<64><<<aggb, 256, 0, stream>>>(T, rowp, edges, dinv, b4, H, N);

    k_gemm<64, 32, false><<<gemmb, 256, 0, stream>>>(H, wt5, T, N);
    k_agg<32><<<aggb, 256, 0, stream>>>(T, rowp, edges, dinv, b5, H, N);

    k_bounds<<<1, 128, 0, stream>>>(batch, gstart, N);
    k_pool2<<<N_GRAPHS, 256, 0, stream>>>(H, gstart, pooled);
    k_fc<<<1, 256, 0, stream>>>(pooled, Wfc, bfc, out);
}